// Round 2
// baseline (61.752 us; speedup 1.0000x reference)
//
#include <hip/hip_runtime.h>

// Consistent-loss kernel: per-column scatter-max into 51 value buckets,
// then masked L1-distance means vs left/right. 256x256 f32, scalar out.
//
// Geometry hard-coded: H=W=256, row split at 128, buckets round(up*50+110)
// in [110,160] (51 slots), mask up >= 0.0235, threshold 0.2.

__global__ __launch_bounds__(256) void consist_loss_kernel(
    const float* __restrict__ up,
    const float* __restrict__ left,
    const float* __restrict__ right,
    float* __restrict__ out) {
#pragma clang fp contract(off)
    const int j = blockIdx.x;    // column of `up` == output row of up2{l,r}
    const int t = threadIdx.x;   // row index i

    __shared__ int u2r[64];      // slots 0..50 hold float bits (nonneg -> int order == float order)
    __shared__ int u2l[64];

    if (t < 64) { u2r[t] = 0; u2l[t] = 0; }
    __syncthreads();

    // ---- Phase A: scatter-max over rows i of column j ----
    const float u = up[t * 256 + j];
    if (u >= 0.0235f) {
        // match XLA: mul then add (no FMA), then round-half-even
        float s = u * 50.0f;
        s = s + 110.0f;
        const int b = (int)rintf(s) - 110;   // 0..50
        if (t > 128) {
            const float v = (float)(t - 128) / 60.0f;   // val_r > 0
            atomicMax(&u2r[b], __float_as_int(v));
        } else if (t < 128) {
            const float v = (float)(128 - t) / 60.0f;   // val_l > 0
            atomicMax(&u2l[b], __float_as_int(v));
        }
        // t == 128: val_l == 0 -> no-op against zero-init buffer
    }
    __syncthreads();

    // ---- Phase B: masked |diff| sums at row j, cols 110..160 ----
    float part = 0.0f;
    if (t < 51) {
        const int c = 110 + t;
        const float ur = __int_as_float(u2r[t]);
        if (ur != 0.0f) {
            const float d = fabsf(ur - right[j * 256 + c]);
            if (d < 0.2f) part += d;
        }
        const float ul = __int_as_float(u2l[t]);
        if (ul != 0.0f) {
            const float d = fabsf(ul - left[j * 256 + c]);
            if (d < 0.2f) part += d;
        }
    }

    // ---- wave-0 reduction (all nonzero parts live in lanes 0..50) ----
    if (t < 64) {
        part += __shfl_down(part, 32);
        part += __shfl_down(part, 16);
        part += __shfl_down(part, 8);
        part += __shfl_down(part, 4);
        part += __shfl_down(part, 2);
        part += __shfl_down(part, 1);
        if (t == 0) {
            // mean(m_r) + mean(m_l) == (sum_r + sum_l) / 65536 (exact pow2 scale)
            atomicAdd(out, part * (1.0f / 65536.0f));
        }
    }
}

extern "C" void kernel_launch(void* const* d_in, const int* in_sizes, int n_in,
                              void* d_out, int out_size, void* d_ws, size_t ws_size,
                              hipStream_t stream) {
    const float* up    = (const float*)d_in[0];
    const float* left  = (const float*)d_in[1];
    const float* right = (const float*)d_in[2];
    float* out = (float*)d_out;

    // d_out is poisoned to 0xAA before every timed launch -> zero it (graph-capturable).
    hipMemsetAsync(out, 0, sizeof(float), stream);
    consist_loss_kernel<<<256, 256, 0, stream>>>(up, left, right, out);
}